// Round 20
// baseline (122.138 us; speedup 1.0000x reference)
//
#include <hip/hip_runtime.h>
#include <math.h>

namespace {
constexpr int kB = 2;
constexpr int kS = 2048;
constexpr int kD = 1024;
constexpr int kH = 16;
constexpr int kHD = 64;
constexpr int kBS = kB * kS;          // 4096 rows
constexpr float kInvScale = 0.03125f; // 1/sqrt(1024), exact power of 2
// Q pre-scale folds log2(e): softmax then uses bare v_exp_f32 (2^x).
constexpr float kQScale = 0.03125f * 1.4426950408889634f;
constexpr int BM = 128, BN = 64, BK = 64;
}

typedef __attribute__((ext_vector_type(8))) short short8;
typedef __attribute__((ext_vector_type(4))) float f32x4;
typedef __attribute__((ext_vector_type(4))) unsigned short u16x4;
typedef __attribute__((ext_vector_type(4))) unsigned int u32x4;

__device__ inline unsigned short f2bf(float f) {
  union { float f; unsigned u; } v;
  v.f = f;
  unsigned r = v.u + 0x7FFFu + ((v.u >> 16) & 1u);  // RNE
  return (unsigned short)(r >> 16);
}

// Pack two f32 -> u32 of 2 bf16 (round-half-up): low = bf16(lo), hi = bf16(hi).
__device__ inline unsigned pack_bf16_pair(float lo, float hi) {
  union { float f; unsigned u; } a, b;
  a.f = hi; b.f = lo;
  return __builtin_amdgcn_perm(a.u + 0x8000u, b.u + 0x8000u, 0x07060302u);
}

__device__ inline void gload_lds16(const unsigned short* g, unsigned short* l) {
  __builtin_amdgcn_global_load_lds(
      (const __attribute__((address_space(1))) void*)g,
      (__attribute__((address_space(3))) void*)l, 16, 0, 0);
}

// ---------------------------------------------------------------------------
// Prep: cast x and the 4 weights to bf16 (packed), fill RoPE cos/sin table.
// ---------------------------------------------------------------------------
__global__ __launch_bounds__(256) void cast_prep_kernel(
    const float* __restrict__ x, const float* __restrict__ Wq,
    const float* __restrict__ Wk, const float* __restrict__ Wv,
    const float* __restrict__ Wo, unsigned short* __restrict__ xb,
    unsigned short* __restrict__ wb, float2* __restrict__ rope) {
  const int tid = blockIdx.x * 256 + threadIdx.x;
  const int stride = gridDim.x * 256;
  for (int i = tid; i < 1048576; i += stride) {
    const float* src;
    unsigned short* dst;
    int off;
    if (i < 524288) {
      src = x; dst = xb; off = i;
    } else {
      const int j = i - 524288;
      const int w = j >> 17;
      src = (w == 0) ? Wq : (w == 1) ? Wk : (w == 2) ? Wv : Wo;
      dst = wb + (size_t)w * (kD * kD);
      off = j & 131071;
    }
    const float4 a = reinterpret_cast<const float4*>(src)[off * 2];
    const float4 b = reinterpret_cast<const float4*>(src)[off * 2 + 1];
    short8 o;
    o[0] = (short)f2bf(a.x); o[1] = (short)f2bf(a.y);
    o[2] = (short)f2bf(a.z); o[3] = (short)f2bf(a.w);
    o[4] = (short)f2bf(b.x); o[5] = (short)f2bf(b.y);
    o[6] = (short)f2bf(b.z); o[7] = (short)f2bf(b.w);
    reinterpret_cast<short8*>(dst)[off] = o;
  }
  for (int i = tid; i < kS * 32; i += stride) {
    const int s = i >> 5;
    const int pr = i & 31;
    const float f = powf(10000.0f, -(float)pr / 32.0f);
    const float ang = (float)s * f;
    rope[i] = make_float2(cosf(ang), sinf(ang));
  }
}

// ---------------------------------------------------------------------------
// Fused QKV bf16 MFMA GEMM: one block computes Q, K AND V for its
// (rt, ct) tile — A staged ONCE per K-step for 3 B-panels (was 3 blocks),
// 48 MFMA per wave per K-step (3x compute per barrier).
// LDS: A 16 KB + 3x B 8 KB = 40 KB. Epilogues identical to verified R19.
// ---------------------------------------------------------------------------
__global__ __launch_bounds__(256) void qkv_fused_kernel(
    const unsigned short* __restrict__ A, const unsigned short* __restrict__ Wb,
    const float* __restrict__ bq, const float* __restrict__ bk,
    const float* __restrict__ bv, const float2* __restrict__ rope,
    unsigned short* __restrict__ qo, unsigned short* __restrict__ ko,
    unsigned short* __restrict__ vo) {
  const int rt = blockIdx.x * BM;
  const int ct = blockIdx.y * BN;
  const int t = threadIdx.x;
  const int wv = t >> 6;
  const int lane = t & 63;
  const int l15 = lane & 15;
  const int lg = lane >> 4;
  const int wr = wv >> 1;   // 0..1: 64-row group
  const int wc = wv & 1;    // 0..1: 32-col group

  __shared__ unsigned short As[BM * BK];      // 16 KB
  __shared__ unsigned short Bs[3][BN * BK];   // 3 x 8 KB

  f32x4 acc[3][4][2];
#pragma unroll
  for (int m3 = 0; m3 < 3; ++m3)
#pragma unroll
    for (int m = 0; m < 4; ++m)
#pragma unroll
      for (int n = 0; n < 2; ++n) acc[m3][m][n] = f32x4{0.f, 0.f, 0.f, 0.f};

  for (int kt = 0; kt < kD / BK; ++kt) {
    const int k0 = kt * BK;
    __syncthreads();
#pragma unroll
    for (int i = 0; i < 4; ++i) {
      const int off = wv * 4096 + i * 1024;
      const int p = off + lane * 16;
      const int row = p >> 7;
      const int src = ((p >> 4) & 7) ^ (row & 7);
      gload_lds16(A + (size_t)(rt + row) * kD + k0 + src * 8, As + off / 2);
    }
#pragma unroll
    for (int m3 = 0; m3 < 3; ++m3)
#pragma unroll
      for (int i = 0; i < 2; ++i) {
        const int off = wv * 2048 + i * 1024;
        const int p = off + lane * 16;
        const int row = p >> 7;
        const int src = ((p >> 4) & 7) ^ (row & 7);
        gload_lds16(Wb + (size_t)m3 * (kD * kD) + (size_t)(ct + row) * kD +
                        k0 + src * 8,
                    &Bs[m3][off / 2]);
      }
    __syncthreads();

#pragma unroll
    for (int ks = 0; ks < 2; ++ks) {
      short8 af[4], bf[3][2];
#pragma unroll
      for (int m = 0; m < 4; ++m) {
        const int row = wr * 64 + m * 16 + l15;
        const int chunk = (ks * 4 + lg) ^ (row & 7);
        af[m] = *reinterpret_cast<const short8*>(&As[row * BK + chunk * 8]);
      }
#pragma unroll
      for (int m3 = 0; m3 < 3; ++m3)
#pragma unroll
        for (int n = 0; n < 2; ++n) {
          const int row = wc * 32 + n * 16 + l15;
          const int chunk = (ks * 4 + lg) ^ (row & 7);
          bf[m3][n] =
              *reinterpret_cast<const short8*>(&Bs[m3][row * BK + chunk * 8]);
        }
      __builtin_amdgcn_s_setprio(1);
#pragma unroll
      for (int m3 = 0; m3 < 3; ++m3)
#pragma unroll
        for (int m = 0; m < 4; ++m)
#pragma unroll
          for (int n = 0; n < 2; ++n)
            acc[m3][m][n] = __builtin_amdgcn_mfma_f32_16x16x32_bf16(
                af[m], bf[m3][n], acc[m3][m][n], 0, 0, 0);
      __builtin_amdgcn_s_setprio(0);
    }
  }

#pragma unroll
  for (int m = 0; m < 4; ++m) {
    const int grow0 = rt + wr * 64 + m * 16 + lg * 4;
    const int bb = grow0 >> 11;
    const int s0 = grow0 & (kS - 1);
#pragma unroll
    for (int n = 0; n < 2; ++n) {
      const int gcol = ct + wc * 32 + n * 16 + l15;
      const int h = gcol >> 6, d = gcol & 63;
      // mode 2: V (+bias) -> transposed [B,H,64,S]
      {
        const float bsv = bv[gcol];
        u16x4 o;
#pragma unroll
        for (int reg = 0; reg < 4; ++reg)
          o[reg] = f2bf(acc[2][m][n][reg] + bsv);
        *reinterpret_cast<u16x4*>(
            &vo[((size_t)(bb * kH + h) * kHD + d) * kS + s0]) = o;
      }
      // modes 0/1: Q (RoPE, *kQScale) and K (RoPE)
      const int pr = d >> 1;
      const float sgn = (d & 1) ? 1.0f : -1.0f;
#pragma unroll
      for (int m3 = 0; m3 < 2; ++m3) {
        const float bsv = (m3 == 0) ? bq[gcol] : bk[gcol];
        const float post = (m3 == 0) ? kQScale : 1.0f;
        unsigned short* __restrict__ dst = (m3 == 0) ? qo : ko;
#pragma unroll
        for (int reg = 0; reg < 4; ++reg) {
          const int s = s0 + reg;
          const float val = acc[m3][m][n][reg] + bsv;
          const float par = __shfl_xor(val, 1);
          const float2 cs = rope[s * 32 + pr];
          const float o = (val * cs.x + par * cs.y * sgn) * post;
          dst[((size_t)(bb * kH + h) * kS + s) * kHD + d] = f2bf(o);
        }
      }
    }
  }
}

// ---------------------------------------------------------------------------
// Out-projection bf16 MFMA GEMM: out = attn @ Wo^T, 128x64 tile, 4 waves.
// (Verified R15 structure, mode-3 path only.)
// ---------------------------------------------------------------------------
__global__ __launch_bounds__(256) void out_proj_kernel(
    const unsigned short* __restrict__ A, const unsigned short* __restrict__ Wb,
    float* __restrict__ outp) {
  const unsigned short* __restrict__ W = Wb + (size_t)3 * (kD * kD);
  const int rt = blockIdx.x * BM;
  const int ct = blockIdx.y * BN;
  const int t = threadIdx.x;
  const int wv = t >> 6;
  const int lane = t & 63;
  const int l15 = lane & 15;
  const int lg = lane >> 4;
  const int wr = wv >> 1;
  const int wc = wv & 1;

  __shared__ unsigned short As[BM * BK];
  __shared__ unsigned short Bs[BN * BK];

  f32x4 acc[4][2];
#pragma unroll
  for (int m = 0; m < 4; ++m)
#pragma unroll
    for (int n = 0; n < 2; ++n) acc[m][n] = f32x4{0.f, 0.f, 0.f, 0.f};

  for (int kt = 0; kt < kD / BK; ++kt) {
    const int k0 = kt * BK;
    __syncthreads();
#pragma unroll
    for (int i = 0; i < 4; ++i) {
      const int off = wv * 4096 + i * 1024;
      const int p = off + lane * 16;
      const int row = p >> 7;
      const int src = ((p >> 4) & 7) ^ (row & 7);
      gload_lds16(A + (size_t)(rt + row) * kD + k0 + src * 8, As + off / 2);
    }
#pragma unroll
    for (int i = 0; i < 2; ++i) {
      const int off = wv * 2048 + i * 1024;
      const int p = off + lane * 16;
      const int row = p >> 7;
      const int src = ((p >> 4) & 7) ^ (row & 7);
      gload_lds16(W + (size_t)(ct + row) * kD + k0 + src * 8, Bs + off / 2);
    }
    __syncthreads();

#pragma unroll
    for (int ks = 0; ks < 2; ++ks) {
      short8 af[4], bf[2];
#pragma unroll
      for (int m = 0; m < 4; ++m) {
        const int row = wr * 64 + m * 16 + l15;
        const int chunk = (ks * 4 + lg) ^ (row & 7);
        af[m] = *reinterpret_cast<const short8*>(&As[row * BK + chunk * 8]);
      }
#pragma unroll
      for (int n = 0; n < 2; ++n) {
        const int row = wc * 32 + n * 16 + l15;
        const int chunk = (ks * 4 + lg) ^ (row & 7);
        bf[n] = *reinterpret_cast<const short8*>(&Bs[row * BK + chunk * 8]);
      }
      __builtin_amdgcn_s_setprio(1);
#pragma unroll
      for (int m = 0; m < 4; ++m)
#pragma unroll
        for (int n = 0; n < 2; ++n)
          acc[m][n] = __builtin_amdgcn_mfma_f32_16x16x32_bf16(
              af[m], bf[n], acc[m][n], 0, 0, 0);
      __builtin_amdgcn_s_setprio(0);
    }
  }

#pragma unroll
  for (int m = 0; m < 4; ++m) {
    const int grow0 = rt + wr * 64 + m * 16 + lg * 4;
#pragma unroll
    for (int n = 0; n < 2; ++n) {
      const int gcol = ct + wc * 32 + n * 16 + l15;
#pragma unroll
      for (int reg = 0; reg < 4; ++reg)
        outp[(size_t)(grow0 + reg) * kD + gcol] = acc[m][n][reg];
    }
  }
}

// ---------------------------------------------------------------------------
// Flash attention, bf16 MFMA, swapped operands, LDS-staged K/V, dbuf.
// 8 waves/block = 4 row-strips (32 q-rows) x 2 kv-groups (32 kv each),
// 128 q-rows/block, KV-step 128 per barrier pair (two [64][64] sub-tiles).
// Softmax: P = 2^S via __builtin_amdgcn_exp2f (log2e folded into Q).
// Unnormalized partials over kv-halves are additive (no max tracking);
// l via ones-MFMA; one-time LDS combine at the end.  (Verified R19.)
// ---------------------------------------------------------------------------
__global__ __launch_bounds__(512) void attn_mfma_kernel(
    const unsigned short* __restrict__ qb, const unsigned short* __restrict__ kb,
    const unsigned short* __restrict__ vtb, unsigned short* __restrict__ attn) {
  const int qt = blockIdx.x;   // 128-row q tile
  const int h = blockIdx.y;
  const int b = blockIdx.z;
  const int t = threadIdx.x;
  const int wave = t >> 6;     // 0..7
  const int lane = t & 63;
  const int l15 = lane & 15;
  const int lg = lane >> 4;
  const int g = wave >> 2;     // kv group (0: kv 0-31, 1: kv 32-63 of sub-tile)
  const int st = wave & 3;     // row strip (32 q-rows)

  // 64.5 KB: K/V double buffers of 2x[2 half][64][64], + combine alias.
  __shared__ __align__(16) unsigned char smem[2 * 16384 + 2 * 16384 + 512];
  unsigned short* Ks0 = (unsigned short*)smem;            // [2 buf][2 hh][64*64]
  unsigned short* Vs0 = (unsigned short*)(smem + 32768);
  float* Ocomb = (float*)smem;                            // [4][32][64] fp32
  float* lcomb = (float*)(smem + 65536);                  // [4][32]

  const size_t bh = (size_t)(b * kH + h);
  const unsigned short* qp = qb + bh * kS * kHD;
  const unsigned short* kp = kb + bh * kS * kHD;
  const unsigned short* vp = vtb + bh * (size_t)kHD * kS;

  const int qrow0 = qt * 128 + st * 32;

  short8 qf[2][2];
#pragma unroll
  for (int qi = 0; qi < 2; ++qi)
#pragma unroll
    for (int f = 0; f < 2; ++f)
      qf[qi][f] = *reinterpret_cast<const short8*>(
          qp + (size_t)(qrow0 + qi * 16 + l15) * kHD + f * 32 + lg * 8);

  short8 ones;
#pragma unroll
  for (int j = 0; j < 8; ++j) ones[j] = (short)0x3F80;  // bf16 1.0

  f32x4 acc_o[2][4], acc_l[2];
#pragma unroll
  for (int qi = 0; qi < 2; ++qi) {
    acc_l[qi] = f32x4{0.f, 0.f, 0.f, 0.f};
#pragma unroll
    for (int ot = 0; ot < 4; ++ot) acc_o[qi][ot] = f32x4{0.f, 0.f, 0.f, 0.f};
  }

  const int srow = t >> 3;                 // LDS row slot 0..63
  const int sc = (t & 7) ^ (srow & 7);     // pre-swizzled source chunk
  const int kvrow = (srow & 0x23) | ((srow & 0x0C) << 1) | ((srow & 0x10) >> 2);
  const int ldsoff = wave * 512;           // wave-uniform dest (ushorts)

  // Prologue: stage tile 0 (both halves) into buf 0.
#pragma unroll
  for (int hh = 0; hh < 2; ++hh) {
    gload_lds16(kp + (size_t)(hh * 64 + kvrow) * kHD + sc * 8,
                &Ks0[hh * 4096 + ldsoff]);
    gload_lds16(vp + (size_t)srow * kS + hh * 64 + sc * 8,
                &Vs0[hh * 4096 + ldsoff]);
  }
  __syncthreads();

  constexpr int NT = kS / 128;  // 16
  for (int kt = 0; kt < NT; ++kt) {
    const int cur = kt & 1;
    unsigned short* Ksb = Ks0 + cur * 8192;
    unsigned short* Vsb = Vs0 + cur * 8192;
    if (kt + 1 < NT) {
      const int nb = (kt + 1) * 128;
#pragma unroll
      for (int hh = 0; hh < 2; ++hh) {
        gload_lds16(kp + (size_t)(nb + hh * 64 + kvrow) * kHD + sc * 8,
                    &Ks0[(cur ^ 1) * 8192 + hh * 4096 + ldsoff]);
        gload_lds16(vp + (size_t)srow * kS + nb + hh * 64 + sc * 8,
                    &Vs0[(cur ^ 1) * 8192 + hh * 4096 + ldsoff]);
      }
    }

#pragma unroll
    for (int hh = 0; hh < 2; ++hh) {
      unsigned short* Ksc = Ksb + hh * 4096;
      unsigned short* Vsc = Vsb + hh * 4096;

      short8 kf[2][2], vf[4];
#pragma unroll
      for (int nt = 0; nt < 2; ++nt) {
        const int row = g * 32 + nt * 16 + l15;
#pragma unroll
        for (int f = 0; f < 2; ++f) {
          const int c = (f * 4 + lg) ^ (row & 7);
          kf[nt][f] = *reinterpret_cast<const short8*>(&Ksc[row * 64 + c * 8]);
        }
      }
#pragma unroll
      for (int ot = 0; ot < 4; ++ot) {
        const int row = ot * 16 + l15;
        const int c = (4 * g + lg) ^ (row & 7);
        vf[ot] = *reinterpret_cast<const short8*>(&Vsc[row * 64 + c * 8]);
      }

      f32x4 acc_s[2][2];
      __builtin_amdgcn_s_setprio(1);
#pragma unroll
      for (int qi = 0; qi < 2; ++qi)
#pragma unroll
        for (int nt = 0; nt < 2; ++nt) {
          acc_s[qi][nt] = __builtin_amdgcn_mfma_f32_16x16x32_bf16(
              kf[nt][0], qf[qi][0], f32x4{0.f, 0.f, 0.f, 0.f}, 0, 0, 0);
          acc_s[qi][nt] = __builtin_amdgcn_mfma_f32_16x16x32_bf16(
              kf[nt][1], qf[qi][1], acc_s[qi][nt], 0, 0, 0);
        }
      __builtin_amdgcn_s_setprio(0);

#pragma unroll
      for (int qi = 0; qi < 2; ++qi) {
        float p[2][4];
#pragma unroll
        for (int nt = 0; nt < 2; ++nt)
#pragma unroll
          for (int r = 0; r < 4; ++r)
            p[nt][r] = __builtin_amdgcn_exp2f(acc_s[qi][nt][r]);

        short8 pb;
        {
          u32x4 w;
          w.x = pack_bf16_pair(p[0][0], p[0][1]);
          w.y = pack_bf16_pair(p[0][2], p[0][3]);
          w.z = pack_bf16_pair(p[1][0], p[1][1]);
          w.w = pack_bf16_pair(p[1][2], p[1][3]);
          pb = *reinterpret_cast<short8*>(&w);
        }

        __builtin_amdgcn_s_setprio(1);
#pragma unroll
        for (int ot = 0; ot < 4; ++ot)
          acc_o[qi][ot] = __builtin_amdgcn_mfma_f32_16x16x32_bf16(
              vf[ot], pb, acc_o[qi][ot], 0, 0, 0);
        acc_l[qi] = __builtin_amdgcn_mfma_f32_16x16x32_bf16(
            ones, pb, acc_l[qi], 0, 0, 0);
        __builtin_amdgcn_s_setprio(0);
      }
    }

    __syncthreads();
  }

  // Epilogue: combine kv-group partials via LDS (aliases finished K/V bufs).
  if (g == 1) {
#pragma unroll
    for (int qi = 0; qi < 2; ++qi) {
      const int row = qi * 16 + l15;
#pragma unroll
      for (int ot = 0; ot < 4; ++ot)
        *reinterpret_cast<f32x4*>(
            &Ocomb[(st * 32 + row) * 64 + ot * 16 + lg * 4]) = acc_o[qi][ot];
      if (lg == 0) lcomb[st * 32 + row] = acc_l[qi][0];
    }
  }
  __syncthreads();
  if (g == 0) {
#pragma unroll
    for (int qi = 0; qi < 2; ++qi) {
      const int row = qi * 16 + l15;
      const float l = acc_l[qi][0] + lcomb[st * 32 + row];
      const float inv_l = 1.0f / l;
      const int s = qrow0 + row;
      unsigned short* __restrict__ dst =
          attn + ((size_t)b * kS + s) * kD + h * kHD;
#pragma unroll
      for (int ot = 0; ot < 4; ++ot) {
        const f32x4 oth = *reinterpret_cast<const f32x4*>(
            &Ocomb[(st * 32 + row) * 64 + ot * 16 + lg * 4]);
        u16x4 o;
        o[0] = f2bf((acc_o[qi][ot][0] + oth[0]) * inv_l);
        o[1] = f2bf((acc_o[qi][ot][1] + oth[1]) * inv_l);
        o[2] = f2bf((acc_o[qi][ot][2] + oth[2]) * inv_l);
        o[3] = f2bf((acc_o[qi][ot][3] + oth[3]) * inv_l);
        *reinterpret_cast<u16x4*>(&dst[ot * 16 + lg * 4]) = o;
      }
    }
  }
}

extern "C" void kernel_launch(void* const* d_in, const int* in_sizes, int n_in,
                              void* d_out, int out_size, void* d_ws,
                              size_t ws_size, hipStream_t stream) {
  (void)in_sizes; (void)n_in; (void)out_size; (void)ws_size;
  const float* x = (const float*)d_in[0];
  const float* Wq = (const float*)d_in[1];
  const float* bq = (const float*)d_in[2];
  const float* Wk = (const float*)d_in[3];
  const float* bk = (const float*)d_in[4];
  const float* Wv = (const float*)d_in[5];
  const float* bv = (const float*)d_in[6];
  const float* Wo = (const float*)d_in[7];
  float* out = (float*)d_out;

  const size_t n = (size_t)kBS * kD;
  float2* rope = (float2*)d_ws;
  unsigned short* xb = (unsigned short*)(rope + kS * 32);
  unsigned short* wb = xb + n;
  unsigned short* qb = wb + 4 * (size_t)kD * kD;
  unsigned short* kb = qb + n;
  unsigned short* vt = kb + n;
  unsigned short* attnb = vt + n;

  cast_prep_kernel<<<2048, 256, 0, stream>>>(x, Wq, Wk, Wv, Wo, xb, wb, rope);

  dim3 gq(kBS / BM, kD / BN);
  qkv_fused_kernel<<<gq, dim3(256), 0, stream>>>(xb, wb, bq, bk, bv, rope, qb,
                                                 kb, vt);

  dim3 ga(kS / 128, kH, kB);
  attn_mfma_kernel<<<ga, dim3(512), 0, stream>>>(qb, kb, vt, attnb);

  dim3 go(kBS / BM, kD / BN);
  out_proj_kernel<<<go, dim3(256), 0, stream>>>(attnb, wb, out);
}

// Round 21
// 105.860 us; speedup vs baseline: 1.1538x; 1.1538x over previous
//
#include <hip/hip_runtime.h>
#include <math.h>

namespace {
constexpr int kB = 2;
constexpr int kS = 2048;
constexpr int kD = 1024;
constexpr int kH = 16;
constexpr int kHD = 64;
constexpr int kBS = kB * kS;          // 4096 rows
constexpr float kInvScale = 0.03125f; // 1/sqrt(1024), exact power of 2
// Q pre-scale folds log2(e): softmax then uses bare v_exp_f32 (2^x).
constexpr float kQScale = 0.03125f * 1.4426950408889634f;
constexpr int BM = 128, BN = 64, BK = 64;
}

typedef __attribute__((ext_vector_type(8))) short short8;
typedef __attribute__((ext_vector_type(4))) float f32x4;
typedef __attribute__((ext_vector_type(4))) unsigned short u16x4;
typedef __attribute__((ext_vector_type(4))) unsigned int u32x4;

__device__ inline unsigned short f2bf(float f) {
  union { float f; unsigned u; } v;
  v.f = f;
  unsigned r = v.u + 0x7FFFu + ((v.u >> 16) & 1u);  // RNE
  return (unsigned short)(r >> 16);
}

// Pack two f32 -> u32 of 2 bf16 (round-half-up): low = bf16(lo), hi = bf16(hi).
__device__ inline unsigned pack_bf16_pair(float lo, float hi) {
  union { float f; unsigned u; } a, b;
  a.f = hi; b.f = lo;
  return __builtin_amdgcn_perm(a.u + 0x8000u, b.u + 0x8000u, 0x07060302u);
}

__device__ inline void gload_lds16(const unsigned short* g, unsigned short* l) {
  __builtin_amdgcn_global_load_lds(
      (const __attribute__((address_space(1))) void*)g,
      (__attribute__((address_space(3))) void*)l, 16, 0, 0);
}

// ---------------------------------------------------------------------------
// Prep: cast x and the 4 weights to bf16 (packed), fill RoPE cos/sin table.
// ---------------------------------------------------------------------------
__global__ __launch_bounds__(256) void cast_prep_kernel(
    const float* __restrict__ x, const float* __restrict__ Wq,
    const float* __restrict__ Wk, const float* __restrict__ Wv,
    const float* __restrict__ Wo, unsigned short* __restrict__ xb,
    unsigned short* __restrict__ wb, float2* __restrict__ rope) {
  const int tid = blockIdx.x * 256 + threadIdx.x;
  const int stride = gridDim.x * 256;
  for (int i = tid; i < 1048576; i += stride) {
    const float* src;
    unsigned short* dst;
    int off;
    if (i < 524288) {
      src = x; dst = xb; off = i;
    } else {
      const int j = i - 524288;
      const int w = j >> 17;
      src = (w == 0) ? Wq : (w == 1) ? Wk : (w == 2) ? Wv : Wo;
      dst = wb + (size_t)w * (kD * kD);
      off = j & 131071;
    }
    const float4 a = reinterpret_cast<const float4*>(src)[off * 2];
    const float4 b = reinterpret_cast<const float4*>(src)[off * 2 + 1];
    short8 o;
    o[0] = (short)f2bf(a.x); o[1] = (short)f2bf(a.y);
    o[2] = (short)f2bf(a.z); o[3] = (short)f2bf(a.w);
    o[4] = (short)f2bf(b.x); o[5] = (short)f2bf(b.y);
    o[6] = (short)f2bf(b.z); o[7] = (short)f2bf(b.w);
    reinterpret_cast<short8*>(dst)[off] = o;
  }
  for (int i = tid; i < kS * 32; i += stride) {
    const int s = i >> 5;
    const int pr = i & 31;
    const float f = powf(10000.0f, -(float)pr / 32.0f);
    const float ang = (float)s * f;
    rope[i] = make_float2(cosf(ang), sinf(ang));
  }
}

// ---------------------------------------------------------------------------
// bf16 MFMA GEMM: Y = A @ W^T (+bias), 128x64 tile, BK=64, 4 waves
// (wave = 64x32 sub-tile). 6 resident blocks/CU.  (Verified R15/R19.)
// mode 0: Q (+bias, RoPE, *kQScale) -> bf16 [B,H,S,64]
// mode 1: K (+bias, RoPE)           -> bf16 [B,H,S,64]
// mode 2: V (+bias)                 -> bf16 [B,H,64,S] (transposed)
// mode 3: out-proj                  -> fp32 [B*S, D]
// ---------------------------------------------------------------------------
__global__ __launch_bounds__(256) void gemm_bt_kernel(
    const unsigned short* __restrict__ A, const unsigned short* __restrict__ Wb,
    const float* __restrict__ bq, const float* __restrict__ bk,
    const float* __restrict__ bv, const float2* __restrict__ rope,
    unsigned short* __restrict__ qo, unsigned short* __restrict__ ko,
    unsigned short* __restrict__ vo, float* __restrict__ outp, int mode_base) {
  const int mode = mode_base + blockIdx.z;
  const unsigned short* __restrict__ W = Wb + (size_t)mode * (kD * kD);
  const int rt = blockIdx.x * BM;
  const int ct = blockIdx.y * BN;
  const int t = threadIdx.x;
  const int wv = t >> 6;
  const int lane = t & 63;
  const int l15 = lane & 15;
  const int lg = lane >> 4;
  const int wr = wv >> 1;   // 0..1: 64-row group
  const int wc = wv & 1;    // 0..1: 32-col group

  __shared__ unsigned short As[BM * BK];  // 16 KB
  __shared__ unsigned short Bs[BN * BK];  // 8 KB

  f32x4 acc[4][2];
#pragma unroll
  for (int m = 0; m < 4; ++m)
#pragma unroll
    for (int n = 0; n < 2; ++n) acc[m][n] = f32x4{0.f, 0.f, 0.f, 0.f};

  for (int kt = 0; kt < kD / BK; ++kt) {
    const int k0 = kt * BK;
    __syncthreads();
#pragma unroll
    for (int i = 0; i < 4; ++i) {
      const int off = wv * 4096 + i * 1024;
      const int p = off + lane * 16;
      const int row = p >> 7;
      const int src = ((p >> 4) & 7) ^ (row & 7);
      gload_lds16(A + (size_t)(rt + row) * kD + k0 + src * 8, As + off / 2);
    }
#pragma unroll
    for (int i = 0; i < 2; ++i) {
      const int off = wv * 2048 + i * 1024;
      const int p = off + lane * 16;
      const int row = p >> 7;
      const int src = ((p >> 4) & 7) ^ (row & 7);
      gload_lds16(W + (size_t)(ct + row) * kD + k0 + src * 8, Bs + off / 2);
    }
    __syncthreads();

#pragma unroll
    for (int ks = 0; ks < 2; ++ks) {
      short8 af[4], bf[2];
#pragma unroll
      for (int m = 0; m < 4; ++m) {
        const int row = wr * 64 + m * 16 + l15;
        const int chunk = (ks * 4 + lg) ^ (row & 7);
        af[m] = *reinterpret_cast<const short8*>(&As[row * BK + chunk * 8]);
      }
#pragma unroll
      for (int n = 0; n < 2; ++n) {
        const int row = wc * 32 + n * 16 + l15;
        const int chunk = (ks * 4 + lg) ^ (row & 7);
        bf[n] = *reinterpret_cast<const short8*>(&Bs[row * BK + chunk * 8]);
      }
      __builtin_amdgcn_s_setprio(1);
#pragma unroll
      for (int m = 0; m < 4; ++m)
#pragma unroll
        for (int n = 0; n < 2; ++n)
          acc[m][n] = __builtin_amdgcn_mfma_f32_16x16x32_bf16(
              af[m], bf[n], acc[m][n], 0, 0, 0);
      __builtin_amdgcn_s_setprio(0);
    }
  }

#pragma unroll
  for (int m = 0; m < 4; ++m) {
    const int grow0 = rt + wr * 64 + m * 16 + lg * 4;
    const int bb = grow0 >> 11;
    const int s0 = grow0 & (kS - 1);
#pragma unroll
    for (int n = 0; n < 2; ++n) {
      const int gcol = ct + wc * 32 + n * 16 + l15;
      if (mode == 3) {
#pragma unroll
        for (int reg = 0; reg < 4; ++reg)
          outp[(size_t)(grow0 + reg) * kD + gcol] = acc[m][n][reg];
      } else if (mode == 2) {
        const float bsv = bv[gcol];
        const int h = gcol >> 6, d = gcol & 63;
        u16x4 o;
#pragma unroll
        for (int reg = 0; reg < 4; ++reg)
          o[reg] = f2bf(acc[m][n][reg] + bsv);
        *reinterpret_cast<u16x4*>(
            &vo[((size_t)(bb * kH + h) * kHD + d) * kS + s0]) = o;
      } else {
        const float bsv = (mode == 0) ? bq[gcol] : bk[gcol];
        const float post = (mode == 0) ? kQScale : 1.0f;
        unsigned short* __restrict__ dst = (mode == 0) ? qo : ko;
        const int h = gcol >> 6, d = gcol & 63;
        const int pr = d >> 1;
        const float sgn = (d & 1) ? 1.0f : -1.0f;
#pragma unroll
        for (int reg = 0; reg < 4; ++reg) {
          const int s = s0 + reg;
          const float val = acc[m][n][reg] + bsv;
          const float par = __shfl_xor(val, 1);
          const float2 cs = rope[s * 32 + pr];
          const float o = (val * cs.x + par * cs.y * sgn) * post;
          dst[((size_t)(bb * kH + h) * kS + s) * kHD + d] = f2bf(o);
        }
      }
    }
  }
}

// ---------------------------------------------------------------------------
// Flash attention, bf16 MFMA, swapped operands, LDS-staged K/V, dbuf.
// 8 waves/block = 4 row-strips (32 q-rows) x 2 kv-groups (32 kv each),
// 128 q-rows/block, KV-step 128 per barrier pair (two [64][64] sub-tiles).
// Softmax: P = 2^S via __builtin_amdgcn_exp2f (log2e folded into Q).
// Unnormalized partials over kv-halves are additive (no max tracking);
// l via ones-MFMA; one-time LDS combine at the end.  (Verified R19.)
// ---------------------------------------------------------------------------
__global__ __launch_bounds__(512) void attn_mfma_kernel(
    const unsigned short* __restrict__ qb, const unsigned short* __restrict__ kb,
    const unsigned short* __restrict__ vtb, unsigned short* __restrict__ attn) {
  const int qt = blockIdx.x;   // 128-row q tile
  const int h = blockIdx.y;
  const int b = blockIdx.z;
  const int t = threadIdx.x;
  const int wave = t >> 6;     // 0..7
  const int lane = t & 63;
  const int l15 = lane & 15;
  const int lg = lane >> 4;
  const int g = wave >> 2;     // kv group (0: kv 0-31, 1: kv 32-63 of sub-tile)
  const int st = wave & 3;     // row strip (32 q-rows)

  // 64.5 KB: K/V double buffers of 2x[2 half][64][64], + combine alias.
  __shared__ __align__(16) unsigned char smem[2 * 16384 + 2 * 16384 + 512];
  unsigned short* Ks0 = (unsigned short*)smem;            // [2 buf][2 hh][64*64]
  unsigned short* Vs0 = (unsigned short*)(smem + 32768);
  float* Ocomb = (float*)smem;                            // [4][32][64] fp32
  float* lcomb = (float*)(smem + 65536);                  // [4][32]

  const size_t bh = (size_t)(b * kH + h);
  const unsigned short* qp = qb + bh * kS * kHD;
  const unsigned short* kp = kb + bh * kS * kHD;
  const unsigned short* vp = vtb + bh * (size_t)kHD * kS;

  const int qrow0 = qt * 128 + st * 32;

  short8 qf[2][2];
#pragma unroll
  for (int qi = 0; qi < 2; ++qi)
#pragma unroll
    for (int f = 0; f < 2; ++f)
      qf[qi][f] = *reinterpret_cast<const short8*>(
          qp + (size_t)(qrow0 + qi * 16 + l15) * kHD + f * 32 + lg * 8);

  short8 ones;
#pragma unroll
  for (int j = 0; j < 8; ++j) ones[j] = (short)0x3F80;  // bf16 1.0

  f32x4 acc_o[2][4], acc_l[2];
#pragma unroll
  for (int qi = 0; qi < 2; ++qi) {
    acc_l[qi] = f32x4{0.f, 0.f, 0.f, 0.f};
#pragma unroll
    for (int ot = 0; ot < 4; ++ot) acc_o[qi][ot] = f32x4{0.f, 0.f, 0.f, 0.f};
  }

  const int srow = t >> 3;                 // LDS row slot 0..63
  const int sc = (t & 7) ^ (srow & 7);     // pre-swizzled source chunk
  const int kvrow = (srow & 0x23) | ((srow & 0x0C) << 1) | ((srow & 0x10) >> 2);
  const int ldsoff = wave * 512;           // wave-uniform dest (ushorts)

  // Prologue: stage tile 0 (both halves) into buf 0.
#pragma unroll
  for (int hh = 0; hh < 2; ++hh) {
    gload_lds16(kp + (size_t)(hh * 64 + kvrow) * kHD + sc * 8,
                &Ks0[hh * 4096 + ldsoff]);
    gload_lds16(vp + (size_t)srow * kS + hh * 64 + sc * 8,
                &Vs0[hh * 4096 + ldsoff]);
  }
  __syncthreads();

  constexpr int NT = kS / 128;  // 16
  for (int kt = 0; kt < NT; ++kt) {
    const int cur = kt & 1;
    unsigned short* Ksb = Ks0 + cur * 8192;
    unsigned short* Vsb = Vs0 + cur * 8192;
    if (kt + 1 < NT) {
      const int nb = (kt + 1) * 128;
#pragma unroll
      for (int hh = 0; hh < 2; ++hh) {
        gload_lds16(kp + (size_t)(nb + hh * 64 + kvrow) * kHD + sc * 8,
                    &Ks0[(cur ^ 1) * 8192 + hh * 4096 + ldsoff]);
        gload_lds16(vp + (size_t)srow * kS + nb + hh * 64 + sc * 8,
                    &Vs0[(cur ^ 1) * 8192 + hh * 4096 + ldsoff]);
      }
    }

#pragma unroll
    for (int hh = 0; hh < 2; ++hh) {
      unsigned short* Ksc = Ksb + hh * 4096;
      unsigned short* Vsc = Vsb + hh * 4096;

      short8 kf[2][2], vf[4];
#pragma unroll
      for (int nt = 0; nt < 2; ++nt) {
        const int row = g * 32 + nt * 16 + l15;
#pragma unroll
        for (int f = 0; f < 2; ++f) {
          const int c = (f * 4 + lg) ^ (row & 7);
          kf[nt][f] = *reinterpret_cast<const short8*>(&Ksc[row * 64 + c * 8]);
        }
      }
#pragma unroll
      for (int ot = 0; ot < 4; ++ot) {
        const int row = ot * 16 + l15;
        const int c = (4 * g + lg) ^ (row & 7);
        vf[ot] = *reinterpret_cast<const short8*>(&Vsc[row * 64 + c * 8]);
      }

      f32x4 acc_s[2][2];
      __builtin_amdgcn_s_setprio(1);
#pragma unroll
      for (int qi = 0; qi < 2; ++qi)
#pragma unroll
        for (int nt = 0; nt < 2; ++nt) {
          acc_s[qi][nt] = __builtin_amdgcn_mfma_f32_16x16x32_bf16(
              kf[nt][0], qf[qi][0], f32x4{0.f, 0.f, 0.f, 0.f}, 0, 0, 0);
          acc_s[qi][nt] = __builtin_amdgcn_mfma_f32_16x16x32_bf16(
              kf[nt][1], qf[qi][1], acc_s[qi][nt], 0, 0, 0);
        }
      __builtin_amdgcn_s_setprio(0);

#pragma unroll
      for (int qi = 0; qi < 2; ++qi) {
        float p[2][4];
#pragma unroll
        for (int nt = 0; nt < 2; ++nt)
#pragma unroll
          for (int r = 0; r < 4; ++r)
            p[nt][r] = __builtin_amdgcn_exp2f(acc_s[qi][nt][r]);

        short8 pb;
        {
          u32x4 w;
          w.x = pack_bf16_pair(p[0][0], p[0][1]);
          w.y = pack_bf16_pair(p[0][2], p[0][3]);
          w.z = pack_bf16_pair(p[1][0], p[1][1]);
          w.w = pack_bf16_pair(p[1][2], p[1][3]);
          pb = *reinterpret_cast<short8*>(&w);
        }

        __builtin_amdgcn_s_setprio(1);
#pragma unroll
        for (int ot = 0; ot < 4; ++ot)
          acc_o[qi][ot] = __builtin_amdgcn_mfma_f32_16x16x32_bf16(
              vf[ot], pb, acc_o[qi][ot], 0, 0, 0);
        acc_l[qi] = __builtin_amdgcn_mfma_f32_16x16x32_bf16(
            ones, pb, acc_l[qi], 0, 0, 0);
        __builtin_amdgcn_s_setprio(0);
      }
    }

    __syncthreads();
  }

  // Epilogue: combine kv-group partials via LDS (aliases finished K/V bufs).
  if (g == 1) {
#pragma unroll
    for (int qi = 0; qi < 2; ++qi) {
      const int row = qi * 16 + l15;
#pragma unroll
      for (int ot = 0; ot < 4; ++ot)
        *reinterpret_cast<f32x4*>(
            &Ocomb[(st * 32 + row) * 64 + ot * 16 + lg * 4]) = acc_o[qi][ot];
      if (lg == 0) lcomb[st * 32 + row] = acc_l[qi][0];
    }
  }
  __syncthreads();
  if (g == 0) {
#pragma unroll
    for (int qi = 0; qi < 2; ++qi) {
      const int row = qi * 16 + l15;
      const float l = acc_l[qi][0] + lcomb[st * 32 + row];
      const float inv_l = 1.0f / l;
      const int s = qrow0 + row;
      unsigned short* __restrict__ dst =
          attn + ((size_t)b * kS + s) * kD + h * kHD;
#pragma unroll
      for (int ot = 0; ot < 4; ++ot) {
        const f32x4 oth = *reinterpret_cast<const f32x4*>(
            &Ocomb[(st * 32 + row) * 64 + ot * 16 + lg * 4]);
        u16x4 o;
        o[0] = f2bf((acc_o[qi][ot][0] + oth[0]) * inv_l);
        o[1] = f2bf((acc_o[qi][ot][1] + oth[1]) * inv_l);
        o[2] = f2bf((acc_o[qi][ot][2] + oth[2]) * inv_l);
        o[3] = f2bf((acc_o[qi][ot][3] + oth[3]) * inv_l);
        *reinterpret_cast<u16x4*>(&dst[ot * 16 + lg * 4]) = o;
      }
    }
  }
}

extern "C" void kernel_launch(void* const* d_in, const int* in_sizes, int n_in,
                              void* d_out, int out_size, void* d_ws,
                              size_t ws_size, hipStream_t stream) {
  (void)in_sizes; (void)n_in; (void)out_size; (void)ws_size;
  const float* x = (const float*)d_in[0];
  const float* Wq = (const float*)d_in[1];
  const float* bq = (const float*)d_in[2];
  const float* Wk = (const float*)d_in[3];
  const float* bk = (const float*)d_in[4];
  const float* Wv = (const float*)d_in[5];
  const float* bv = (const float*)d_in[6];
  const float* Wo = (const float*)d_in[7];
  float* out = (float*)d_out;

  const size_t n = (size_t)kBS * kD;
  float2* rope = (float2*)d_ws;
  unsigned short* xb = (unsigned short*)(rope + kS * 32);
  unsigned short* wb = xb + n;
  unsigned short* qb = wb + 4 * (size_t)kD * kD;
  unsigned short* kb = qb + n;
  unsigned short* vt = kb + n;
  unsigned short* attnb = vt + n;

  cast_prep_kernel<<<2048, 256, 0, stream>>>(x, Wq, Wk, Wv, Wo, xb, wb, rope);

  dim3 gq(kBS / BM, kD / BN, 3);
  gemm_bt_kernel<<<gq, dim3(256), 0, stream>>>(xb, wb, bq, bk, bv, rope, qb,
                                               kb, vt, nullptr, 0);

  dim3 ga(kS / 128, kH, kB);
  attn_mfma_kernel<<<ga, dim3(512), 0, stream>>>(qb, kb, vt, attnb);

  dim3 go(kBS / BM, kD / BN, 1);
  gemm_bt_kernel<<<go, dim3(256), 0, stream>>>(attnb, wb, bq, bk, bv, rope, qb,
                                               kb, vt, out, 3);
}